// Round 18
// baseline (781.914 us; speedup 1.0000x reference)
//
#include <hip/hip_runtime.h>
#include <hip/hip_cooperative_groups.h>

namespace cg = cooperative_groups;

#define N_NODES 51200
#define N_EDGES 819200
#define HDIM 128
#define AK 256          // GEMM K = 2*HDIM (agg | x)
#define NGRAPH 128
#define SEG 400
#define NOUT 10
#define SLOT 64         // fixed col2 slot per node (deg ~ Poisson(16); P(>64) ~ 1e-13)
#define NBLK 256        // 1 block/CU -> cooperative co-residency trivially valid
#define NTHR 1024
#define NWAVE (NBLK * (NTHR / 64))   // 4096 waves

typedef unsigned short ushort_t;
typedef unsigned int uint_t;
typedef __attribute__((ext_vector_type(8))) short bf16x8;
typedef __attribute__((ext_vector_type(16))) float f32x16;

static __device__ __forceinline__ unsigned short f2bf(float f) {
    unsigned int u = __float_as_uint(f);
    unsigned int r = (u + 0x7fffu + ((u >> 16) & 1u)) >> 16;  // RNE
    return (unsigned short)r;
}
static __device__ __forceinline__ float bf2f(unsigned short h) {
    return __uint_as_float(((unsigned int)h) << 16);
}

// ONE cooperative kernel: prep | scatter | 3x(agg | gemm | mixup) | final.
// Rationale: R17 showed ~110us of inter-dispatch gaps (~10-15us each, confirmed
// R13->R14); grid.sync() with only 256 block-arrivals costs ~3-4us (R11 atomic
// model). Phase bodies are R16's proven kernels, grid-strided.
// Lessons kept: all __shfl with full exec (R10); no single-address hot atomics
// (R11); scatter is contention-floor-limited (R15/R16); agg phase stays
// resource-lean so 16 waves/CU all gather (R17).

__global__ __launch_bounds__(NTHR, 4) void k_mega(
    const float* __restrict__ x0, const int* __restrict__ src, const int* __restrict__ dst,
    const float* __restrict__ lam, const int* __restrict__ perm1, const int* __restrict__ perm2,
    const float* __restrict__ W1rel, const float* __restrict__ b1rel, const float* __restrict__ W1root,
    const float* __restrict__ W2rel, const float* __restrict__ b2rel, const float* __restrict__ W2root,
    const float* __restrict__ Wlin, const float* __restrict__ blin, float* __restrict__ out,
    int* __restrict__ cnt, ushort_t* __restrict__ col2, ushort_t* __restrict__ Abuf,
    ushort_t* __restrict__ ybuf, ushort_t* __restrict__ Wfrag1, ushort_t* __restrict__ Wfrag2,
    float* __restrict__ pooled)
{
    cg::grid_group grid = cg::this_grid();
    int tid = threadIdx.x;
    int gWave = blockIdx.x * (NTHR / 64) + (tid >> 6);
    int lane = tid & 63;

    // ---- P0: init (cast x0 -> Abuf right half, Wfrags, pooled=0, cnt=0) ----
    {
        int grp = blockIdx.x * 4 + (tid >> 8);
        int t256 = tid & 255;
        for (int b = grp; b < 6920; b += NBLK * 4) {
            if (b < 6400) {
                int idx = b * 256 + t256;
                int row = idx >> 5;
                int c4 = (idx & 31) * 4;
                float4 v = *(const float4*)(x0 + (size_t)row * HDIM + c4);
                ushort4 h;
                h.x = f2bf(v.x); h.y = f2bf(v.y); h.z = f2bf(v.z); h.w = f2bf(v.w);
                *(ushort4*)(Abuf + (size_t)row * AK + HDIM + c4) = h;
            } else if (b < 6656) {
                int w2 = (b >= 6528);
                int t = (b - (w2 ? 6528 : 6400)) * 256 + t256;  // 0..32767
                const float* Wrel  = w2 ? W2rel : W1rel;
                const float* Wroot = w2 ? W2root : W1root;
                ushort_t* dstF     = w2 ? Wfrag2 : Wfrag1;
                int j = t & 7;
                int l = (t >> 3) & 63;
                int s = (t >> 9) & 15;
                int tt = t >> 13;
                int k = 16 * s + (l >> 5) * 8 + j;
                int n = 32 * tt + (l & 31);
                float v = (k < HDIM) ? Wrel[(size_t)k * HDIM + n]
                                     : Wroot[(size_t)(k - HDIM) * HDIM + n];
                dstF[t] = f2bf(v);
            } else if (b < 6720) {
                pooled[(b - 6656) * 256 + t256] = 0.f;
            } else {
                cnt[(b - 6720) * 256 + t256] = 0;
            }
        }
    }
    grid.sync();

    // ---- P1: edge scatter (contention-limited floor, R14/R16) ----
    {
        int gtid = blockIdx.x * NTHR + tid;
        for (int e = gtid; e < N_EDGES; e += NBLK * NTHR) {
            int d = dst[e];
            int pos = atomicAdd(&cnt[d], 1);
            col2[(size_t)d * SLOT + pos] = (ushort_t)src[e];
        }
    }
    grid.sync();

    // ---- layers ----
    for (int layer = 0; layer < 3; ++layer) {
        const ushort_t* Wf  = (layer == 0) ? Wfrag1 : Wfrag2;
        const float* bias   = (layer == 0) ? b1rel : b2rel;

        // -- aggregate: wave/node, quad-edge 16B gathers (R13), writes Abuf left --
        {
            int il = lane & 15;
            int qe = lane >> 4;
            const ushort_t* xsrc = Abuf + HDIM + (size_t)il * 8;
            for (int node = gWave; node < N_NODES; node += NWAVE) {
                int beg = node * SLOT;
                int end = beg + cnt[node];

                float a[4][8];
#pragma unroll
                for (int j = 0; j < 4; ++j)
#pragma unroll
                    for (int k = 0; k < 8; ++k) a[j][k] = 0.f;

                int e = beg;
                for (; e + 16 <= end; e += 16) {
                    int c[4];
#pragma unroll
                    for (int j = 0; j < 4; ++j) c[j] = (int)col2[e + 4 * j + qe];
#pragma unroll
                    for (int j = 0; j < 4; ++j) {
                        uint4 v = *(const uint4*)(xsrc + (size_t)c[j] * AK);
                        a[j][0] += __uint_as_float(v.x << 16);
                        a[j][1] += __uint_as_float(v.x & 0xffff0000u);
                        a[j][2] += __uint_as_float(v.y << 16);
                        a[j][3] += __uint_as_float(v.y & 0xffff0000u);
                        a[j][4] += __uint_as_float(v.z << 16);
                        a[j][5] += __uint_as_float(v.z & 0xffff0000u);
                        a[j][6] += __uint_as_float(v.w << 16);
                        a[j][7] += __uint_as_float(v.w & 0xffff0000u);
                    }
                }
                for (; e + 4 <= end; e += 4) {
                    int c = (int)col2[e + qe];
                    uint4 v = *(const uint4*)(xsrc + (size_t)c * AK);
                    a[0][0] += __uint_as_float(v.x << 16);
                    a[0][1] += __uint_as_float(v.x & 0xffff0000u);
                    a[0][2] += __uint_as_float(v.y << 16);
                    a[0][3] += __uint_as_float(v.y & 0xffff0000u);
                    a[0][4] += __uint_as_float(v.z << 16);
                    a[0][5] += __uint_as_float(v.z & 0xffff0000u);
                    a[0][6] += __uint_as_float(v.w << 16);
                    a[0][7] += __uint_as_float(v.w & 0xffff0000u);
                }
                if (e < end) {
                    int idx = e + qe;
                    bool ok = idx < end;
                    int c = (int)col2[ok ? idx : e];
                    uint4 v = *(const uint4*)(xsrc + (size_t)c * AK);
                    a[1][0] += ok ? __uint_as_float(v.x << 16) : 0.f;
                    a[1][1] += ok ? __uint_as_float(v.x & 0xffff0000u) : 0.f;
                    a[1][2] += ok ? __uint_as_float(v.y << 16) : 0.f;
                    a[1][3] += ok ? __uint_as_float(v.y & 0xffff0000u) : 0.f;
                    a[1][4] += ok ? __uint_as_float(v.z << 16) : 0.f;
                    a[1][5] += ok ? __uint_as_float(v.z & 0xffff0000u) : 0.f;
                    a[1][6] += ok ? __uint_as_float(v.w << 16) : 0.f;
                    a[1][7] += ok ? __uint_as_float(v.w & 0xffff0000u) : 0.f;
                }

                float s[8];
#pragma unroll
                for (int k = 0; k < 8; ++k) {
                    s[k] = (a[0][k] + a[1][k]) + (a[2][k] + a[3][k]);
                    s[k] += __shfl_xor(s[k], 16);   // all lanes execute (R10)
                    s[k] += __shfl_xor(s[k], 32);
                }
                if (qe == 0) {
                    uint4 o;
                    o.x = (uint_t)f2bf(s[0]) | ((uint_t)f2bf(s[1]) << 16);
                    o.y = (uint_t)f2bf(s[2]) | ((uint_t)f2bf(s[3]) << 16);
                    o.z = (uint_t)f2bf(s[4]) | ((uint_t)f2bf(s[5]) << 16);
                    o.w = (uint_t)f2bf(s[6]) | ((uint_t)f2bf(s[7]) << 16);
                    *(uint4*)(Abuf + (size_t)node * AK + il * 8) = o;
                }
            }
        }
        grid.sync();

        if (layer < 2) {
            // -- gemm: wave = 32 rows x 64 cols; direct strided bf16 stores --
            for (int u = gWave; u < 3200; u += NWAVE) {
                int nh = u & 1;
                int row0 = (u >> 1) * 32;
                int m = lane & 31;
                int half = lane >> 5;

                f32x16 acc[2];
#pragma unroll
                for (int t = 0; t < 2; ++t) acc[t] = (f32x16)(0.f);
                float bb[2];
#pragma unroll
                for (int t = 0; t < 2; ++t) bb[t] = bias[nh * 64 + t * 32 + m];

                const ushort_t* arow = Abuf + (size_t)(row0 + m) * AK + half * 8;
                const ushort_t* wf = Wf + (size_t)lane * 8 + (size_t)nh * 2 * 16 * 512;

#pragma unroll
                for (int s = 0; s < 16; ++s) {
                    bf16x8 afrag = *(const bf16x8*)(arow + s * 16);
#pragma unroll
                    for (int t = 0; t < 2; ++t) {
                        bf16x8 bfrag = *(const bf16x8*)(wf + (size_t)(t * 16 + s) * 512);
                        acc[t] = __builtin_amdgcn_mfma_f32_32x32x16_bf16(afrag, bfrag, acc[t], 0, 0, 0);
                    }
                }
#pragma unroll
                for (int t = 0; t < 2; ++t) {
                    int coln = nh * 64 + t * 32 + m;
#pragma unroll
                    for (int r = 0; r < 16; ++r) {
                        int row = row0 + (r & 3) + 8 * (r >> 2) + 4 * half;
                        ybuf[(size_t)row * HDIM + coln] = f2bf(fmaxf(acc[t][r] + bb[t], 0.f));
                    }
                }
            }
            grid.sync();

            // -- mixup: ybuf -> Abuf right half --
            {
                const int* perm = (layer == 0) ? perm1 : perm2;
                float l = lam[0];
                float om = 1.f - l;
                int gtid = blockIdx.x * NTHR + tid;
                for (int idx = gtid; idx < N_NODES * 32; idx += NBLK * NTHR) {
                    int row = idx >> 5;
                    int c4 = (idx & 31) * 4;
                    int p = perm[row];
                    ushort4 a = *(const ushort4*)(ybuf + (size_t)row * HDIM + c4);
                    ushort4 b = *(const ushort4*)(ybuf + (size_t)p * HDIM + c4);
                    ushort4 o;
                    o.x = f2bf(l * bf2f(a.x) + om * bf2f(b.x));
                    o.y = f2bf(l * bf2f(a.y) + om * bf2f(b.y));
                    o.z = f2bf(l * bf2f(a.z) + om * bf2f(b.z));
                    o.w = f2bf(l * bf2f(a.w) + om * bf2f(b.w));
                    *(ushort4*)(Abuf + (size_t)row * AK + HDIM + c4) = o;
                }
            }
            grid.sync();
        } else {
            // -- layer-3 gemm + pooled (mixup3 is a pooling no-op) --
            for (int u = gWave; u < 3200; u += NWAVE) {
                int nh = u & 1;
                int row0 = (u >> 1) * 32;
                int m = lane & 31;
                int half = lane >> 5;

                f32x16 acc[2];
#pragma unroll
                for (int t = 0; t < 2; ++t) acc[t] = (f32x16)(0.f);
                float bb[2];
#pragma unroll
                for (int t = 0; t < 2; ++t) bb[t] = bias[nh * 64 + t * 32 + m];

                const ushort_t* arow = Abuf + (size_t)(row0 + m) * AK + half * 8;
                const ushort_t* wf = Wf + (size_t)lane * 8 + (size_t)nh * 2 * 16 * 512;

#pragma unroll
                for (int s = 0; s < 16; ++s) {
                    bf16x8 afrag = *(const bf16x8*)(arow + s * 16);
#pragma unroll
                    for (int t = 0; t < 2; ++t) {
                        bf16x8 bfrag = *(const bf16x8*)(wf + (size_t)(t * 16 + s) * 512);
                        acc[t] = __builtin_amdgcn_mfma_f32_32x32x16_bf16(afrag, bfrag, acc[t], 0, 0, 0);
                    }
                }

                int g0 = row0 / SEG;
                int bnd = (g0 + 1) * SEG;
                int straddle = (row0 + 31 >= bnd);

#pragma unroll
                for (int t = 0; t < 2; ++t) {
                    float s0 = 0.f, s1 = 0.f;
#pragma unroll
                    for (int r = 0; r < 16; ++r) {
                        int row = row0 + (r & 3) + 8 * (r >> 2) + 4 * half;
                        float v = fmaxf(acc[t][r] + bb[t], 0.f);
                        if (row < bnd) s0 += v; else s1 += v;
                    }
                    s0 += __shfl_xor(s0, 32);
                    s1 += __shfl_xor(s1, 32);
                    if (half == 0) {
                        int coln = nh * 64 + t * 32 + m;
                        atomicAdd(&pooled[g0 * HDIM + coln], s0);
                        if (straddle) atomicAdd(&pooled[(g0 + 1) * HDIM + coln], s1);
                    }
                }
            }
            grid.sync();
        }
    }

    // ---- final: linear + log_softmax, one wave per graph ----
    for (int g = gWave; g < NGRAPH; g += NWAVE) {
        float2 v = *(const float2*)(pooled + (size_t)g * HDIM + lane * 2);
        float p[NOUT];
#pragma unroll
        for (int o = 0; o < NOUT; ++o)
            p[o] = v.x * Wlin[(size_t)(2 * lane) * NOUT + o] +
                   v.y * Wlin[(size_t)(2 * lane + 1) * NOUT + o];
#pragma unroll
        for (int mask = 1; mask < 64; mask <<= 1)
#pragma unroll
            for (int o = 0; o < NOUT; ++o) p[o] += __shfl_xor(p[o], mask);
        if (lane == 0) {
            float lg[NOUT];
            float mx = -1e30f;
#pragma unroll
            for (int o = 0; o < NOUT; ++o) { lg[o] = p[o] + blin[o]; mx = fmaxf(mx, lg[o]); }
            float se = 0.f;
#pragma unroll
            for (int o = 0; o < NOUT; ++o) se += expf(lg[o] - mx);
            float lse = mx + logf(se);
#pragma unroll
            for (int o = 0; o < NOUT; ++o) out[g * NOUT + o] = lg[o] - lse;
        }
    }
}

// ---------------- host ----------------

extern "C" void kernel_launch(void* const* d_in, const int* in_sizes, int n_in,
                              void* d_out, int out_size, void* d_ws, size_t ws_size,
                              hipStream_t stream) {
    const float* x0     = (const float*)d_in[0];
    const int*   edge   = (const int*)d_in[1];
    const int*   src    = edge;
    const int*   dst    = edge + N_EDGES;
    const float* lam    = (const float*)d_in[2];
    const int*   perm1  = (const int*)d_in[5];
    const int*   perm2  = (const int*)d_in[6];
    const float* W1_rel = (const float*)d_in[8];
    const float* b1_rel = (const float*)d_in[9];
    const float* W1_root= (const float*)d_in[10];
    const float* W2_rel = (const float*)d_in[11];
    const float* b2_rel = (const float*)d_in[12];
    const float* W2_root= (const float*)d_in[13];
    const float* W_lin  = (const float*)d_in[14];
    const float* b_lin  = (const float*)d_in[15];
    float* out = (float*)d_out;

    char* w = (char*)d_ws;
    size_t off = 0;
    auto alloc = [&](size_t bytes) -> void* {
        void* p = w + off;
        off = (off + bytes + 255) & ~(size_t)255;
        return p;
    };
    int* cnt        = (int*)alloc((size_t)N_NODES * 4);
    ushort_t* col2  = (ushort_t*)alloc((size_t)N_NODES * SLOT * 2);
    ushort_t* Abuf   = (ushort_t*)alloc((size_t)N_NODES * AK * 2);
    ushort_t* ybuf   = (ushort_t*)alloc((size_t)N_NODES * HDIM * 2);
    ushort_t* Wfrag1 = (ushort_t*)alloc(32768 * 2);
    ushort_t* Wfrag2 = (ushort_t*)alloc(32768 * 2);
    float* pooled    = (float*)alloc((size_t)NGRAPH * HDIM * 4);

    void* args[] = {
        (void*)&x0, (void*)&src, (void*)&dst, (void*)&lam, (void*)&perm1, (void*)&perm2,
        (void*)&W1_rel, (void*)&b1_rel, (void*)&W1_root,
        (void*)&W2_rel, (void*)&b2_rel, (void*)&W2_root,
        (void*)&W_lin, (void*)&b_lin, (void*)&out,
        (void*)&cnt, (void*)&col2, (void*)&Abuf, (void*)&ybuf,
        (void*)&Wfrag1, (void*)&Wfrag2, (void*)&pooled
    };
    hipLaunchCooperativeKernel((const void*)k_mega, dim3(NBLK), dim3(NTHR),
                               args, 0, stream);
}

// Round 19
// 301.758 us; speedup vs baseline: 2.5912x; 2.5912x over previous
//
#include <hip/hip_runtime.h>

#define N_NODES 51200
#define N_EDGES 819200
#define HDIM 128
#define AK 256          // GEMM K = 2*HDIM (agg | x)
#define NGRAPH 128
#define SEG 400
#define NOUT 10
#define SLOT 64         // fixed col2 slot per node (deg ~ Poisson(16); P(>64) ~ 1e-13)

typedef unsigned short ushort_t;
typedef unsigned int uint_t;
typedef __attribute__((ext_vector_type(8))) short bf16x8;
typedef __attribute__((ext_vector_type(16))) float f32x16;

static __device__ __forceinline__ unsigned short f2bf(float f) {
    unsigned int u = __float_as_uint(f);
    unsigned int r = (u + 0x7fffu + ((u >> 16) & 1u)) >> 16;  // RNE
    return (unsigned short)r;
}
static __device__ __forceinline__ float bf2f(unsigned short h) {
    return __uint_as_float(((unsigned int)h) << 16);
}

// ---------------- prep: cast x0, build Wfrags, zero pooled AND cnt ------------------
// grid = 6400 (cast) + 128 (wfrag1) + 128 (wfrag2) + 64 (pooled) + 200 (cnt) = 6920
// Ordered BEFORE scatter (cnt dependency) — replaces the hipMemsetAsync dispatch.

__global__ void k_prep(const float* __restrict__ x, ushort_t* __restrict__ Abuf,
                       const float* __restrict__ W1rel, const float* __restrict__ W1root,
                       const float* __restrict__ W2rel, const float* __restrict__ W2root,
                       ushort_t* __restrict__ Wfrag1, ushort_t* __restrict__ Wfrag2,
                       float* __restrict__ pooled, int* __restrict__ cnt) {
    int b = blockIdx.x;
    if (b < 6400) {
        int idx = b * 256 + threadIdx.x;
        int row = idx >> 5;
        int c4 = (idx & 31) * 4;
        float4 v = *(const float4*)(x + (size_t)row * HDIM + c4);
        ushort4 h;
        h.x = f2bf(v.x); h.y = f2bf(v.y); h.z = f2bf(v.z); h.w = f2bf(v.w);
        *(ushort4*)(Abuf + (size_t)row * AK + HDIM + c4) = h;
    } else if (b < 6656) {
        int w2 = (b >= 6528);
        int tid = (b - (w2 ? 6528 : 6400)) * 256 + threadIdx.x;  // 0..32767
        const float* Wrel  = w2 ? W2rel : W1rel;
        const float* Wroot = w2 ? W2root : W1root;
        ushort_t* dstF     = w2 ? Wfrag2 : Wfrag1;
        int j = tid & 7;
        int l = (tid >> 3) & 63;
        int s = (tid >> 9) & 15;
        int t = tid >> 13;
        int k = 16 * s + (l >> 5) * 8 + j;
        int n = 32 * t + (l & 31);
        float v = (k < HDIM) ? Wrel[(size_t)k * HDIM + n]
                             : Wroot[(size_t)(k - HDIM) * HDIM + n];
        dstF[tid] = f2bf(v);
    } else if (b < 6720) {
        int i = (b - 6656) * 256 + threadIdx.x;  // 0..16383
        pooled[i] = 0.f;
    } else {
        int i = (b - 6720) * 256 + threadIdx.x;  // 0..51199
        cnt[i] = 0;
    }
}

// ---------------- edge scatter: entire CSR build (R14/R16 structure) ----------------
// Contention-limited at the device-coherence point (~6.6 atomics/clk device-wide);
// R15 XCD-slicing and R16 ILP both neutral — this is the CSR floor.
// R18: cooperative mega-kernel regressed 2.6x (grid.sync flushes per-XCD L2).

__global__ void k_scatter(const int* __restrict__ src, const int* __restrict__ dst,
                          int* __restrict__ cnt, ushort_t* __restrict__ col2) {
    int base = blockIdx.x * 1024 + threadIdx.x;
    int d[4], p[4];
#pragma unroll
    for (int k = 0; k < 4; ++k) d[k] = dst[base + k * 256];
#pragma unroll
    for (int k = 0; k < 4; ++k) p[k] = atomicAdd(&cnt[d[k]], 1);
#pragma unroll
    for (int k = 0; k < 4; ++k)
        col2[(size_t)d[k] * SLOT + p[k]] = (ushort_t)src[base + k * 256];
}

// ---------------- aggregation: quad-edge 16B gathers (R13) ----------------

__global__ __launch_bounds__(256) void k_aggregate(ushort_t* __restrict__ Abuf,
                                                   const int* __restrict__ cnt,
                                                   const ushort_t* __restrict__ col) {
    int wave = threadIdx.x >> 6;
    int lane = threadIdx.x & 63;
    int il = lane & 15;          // col group: cols 8*il..8*il+7 (16 B)
    int qe = lane >> 4;          // edge within quad: 0..3
    int node = blockIdx.x * 4 + wave;
    int beg = node * SLOT;
    int end = beg + cnt[node];

    const ushort_t* xsrc = Abuf + HDIM + (size_t)il * 8;

    float a[4][8];
#pragma unroll
    for (int j = 0; j < 4; ++j)
#pragma unroll
        for (int k = 0; k < 8; ++k) a[j][k] = 0.f;

    int e = beg;
    for (; e + 16 <= end; e += 16) {
        int c[4];
#pragma unroll
        for (int j = 0; j < 4; ++j) c[j] = (int)col[e + 4 * j + qe];
#pragma unroll
        for (int j = 0; j < 4; ++j) {
            uint4 v = *(const uint4*)(xsrc + (size_t)c[j] * AK);
            a[j][0] += __uint_as_float(v.x << 16);
            a[j][1] += __uint_as_float(v.x & 0xffff0000u);
            a[j][2] += __uint_as_float(v.y << 16);
            a[j][3] += __uint_as_float(v.y & 0xffff0000u);
            a[j][4] += __uint_as_float(v.z << 16);
            a[j][5] += __uint_as_float(v.z & 0xffff0000u);
            a[j][6] += __uint_as_float(v.w << 16);
            a[j][7] += __uint_as_float(v.w & 0xffff0000u);
        }
    }
    for (; e + 4 <= end; e += 4) {
        int c = (int)col[e + qe];
        uint4 v = *(const uint4*)(xsrc + (size_t)c * AK);
        a[0][0] += __uint_as_float(v.x << 16);
        a[0][1] += __uint_as_float(v.x & 0xffff0000u);
        a[0][2] += __uint_as_float(v.y << 16);
        a[0][3] += __uint_as_float(v.y & 0xffff0000u);
        a[0][4] += __uint_as_float(v.z << 16);
        a[0][5] += __uint_as_float(v.z & 0xffff0000u);
        a[0][6] += __uint_as_float(v.w << 16);
        a[0][7] += __uint_as_float(v.w & 0xffff0000u);
    }
    if (e < end) {
        int idx = e + qe;
        bool ok = idx < end;
        int c = (int)col[ok ? idx : e];
        uint4 v = *(const uint4*)(xsrc + (size_t)c * AK);
        a[1][0] += ok ? __uint_as_float(v.x << 16) : 0.f;
        a[1][1] += ok ? __uint_as_float(v.x & 0xffff0000u) : 0.f;
        a[1][2] += ok ? __uint_as_float(v.y << 16) : 0.f;
        a[1][3] += ok ? __uint_as_float(v.y & 0xffff0000u) : 0.f;
        a[1][4] += ok ? __uint_as_float(v.z << 16) : 0.f;
        a[1][5] += ok ? __uint_as_float(v.z & 0xffff0000u) : 0.f;
        a[1][6] += ok ? __uint_as_float(v.w << 16) : 0.f;
        a[1][7] += ok ? __uint_as_float(v.w & 0xffff0000u) : 0.f;
    }

    float s[8];
#pragma unroll
    for (int k = 0; k < 8; ++k) {
        s[k] = (a[0][k] + a[1][k]) + (a[2][k] + a[3][k]);
        s[k] += __shfl_xor(s[k], 16);   // all lanes execute (R10 bpermute rule)
        s[k] += __shfl_xor(s[k], 32);
    }

    if (qe == 0) {
        uint4 o;
        o.x = (uint_t)f2bf(s[0]) | ((uint_t)f2bf(s[1]) << 16);
        o.y = (uint_t)f2bf(s[2]) | ((uint_t)f2bf(s[3]) << 16);
        o.z = (uint_t)f2bf(s[4]) | ((uint_t)f2bf(s[5]) << 16);
        o.w = (uint_t)f2bf(s[6]) | ((uint_t)f2bf(s[7]) << 16);
        *(uint4*)(Abuf + (size_t)node * AK + il * 8) = o;
    }
}

// ---------------- MFMA GEMM (layers 1-2): split-N, wave = 32 rows x 64 cols ---------

__global__ __launch_bounds__(64) void k_gemm_mfma(const ushort_t* __restrict__ Abuf,
                                                  const ushort_t* __restrict__ Wfrag,
                                                  const float* __restrict__ bias,
                                                  ushort_t* __restrict__ y) {
    __shared__ ushort_t sm[32][72];
    int lane = threadIdx.x;
    int nh = blockIdx.x & 1;
    int row0 = (blockIdx.x >> 1) * 32;
    int m = lane & 31;
    int half = lane >> 5;

    f32x16 acc[2];
#pragma unroll
    for (int t = 0; t < 2; ++t) acc[t] = (f32x16)(0.f);

    float bb[2];
#pragma unroll
    for (int t = 0; t < 2; ++t) bb[t] = bias[nh * 64 + t * 32 + m];

    const ushort_t* arow = Abuf + (size_t)(row0 + m) * AK + half * 8;
    const ushort_t* wf = Wfrag + (size_t)lane * 8 + (size_t)nh * 2 * 16 * 512;

#pragma unroll
    for (int s = 0; s < 16; ++s) {
        bf16x8 afrag = *(const bf16x8*)(arow + s * 16);
#pragma unroll
        for (int t = 0; t < 2; ++t) {
            bf16x8 bfrag = *(const bf16x8*)(wf + (size_t)(t * 16 + s) * 512);
            acc[t] = __builtin_amdgcn_mfma_f32_32x32x16_bf16(afrag, bfrag, acc[t], 0, 0, 0);
        }
    }

#pragma unroll
    for (int t = 0; t < 2; ++t) {
#pragma unroll
        for (int r = 0; r < 16; ++r) {
            int rowL = (r & 3) + 8 * (r >> 2) + 4 * half;
            sm[rowL][t * 32 + m] = f2bf(fmaxf(acc[t][r] + bb[t], 0.f));
        }
    }
    __syncthreads();
    int seg = lane & 7;
    int rbase = lane >> 3;
#pragma unroll
    for (int it = 0; it < 4; ++it) {
        int rowL = rbase + it * 8;
        int4 chunk = *(const int4*)&sm[rowL][seg * 8];
        *(int4*)(y + (size_t)(row0 + rowL) * HDIM + nh * 64 + seg * 8) = chunk;
    }
}

// ---------------- MFMA GEMM layer-3: split-N, relu -> per-graph pooled atomicAdd -----

__global__ __launch_bounds__(64) void k_gemm_pool(const ushort_t* __restrict__ Abuf,
                                                  const ushort_t* __restrict__ Wfrag,
                                                  const float* __restrict__ bias,
                                                  float* __restrict__ pooled) {
    int lane = threadIdx.x;
    int nh = blockIdx.x & 1;
    int row0 = (blockIdx.x >> 1) * 32;
    int m = lane & 31;
    int half = lane >> 5;

    f32x16 acc[2];
#pragma unroll
    for (int t = 0; t < 2; ++t) acc[t] = (f32x16)(0.f);

    float bb[2];
#pragma unroll
    for (int t = 0; t < 2; ++t) bb[t] = bias[nh * 64 + t * 32 + m];

    const ushort_t* arow = Abuf + (size_t)(row0 + m) * AK + half * 8;
    const ushort_t* wf = Wfrag + (size_t)lane * 8 + (size_t)nh * 2 * 16 * 512;

#pragma unroll
    for (int s = 0; s < 16; ++s) {
        bf16x8 afrag = *(const bf16x8*)(arow + s * 16);
#pragma unroll
        for (int t = 0; t < 2; ++t) {
            bf16x8 bfrag = *(const bf16x8*)(wf + (size_t)(t * 16 + s) * 512);
            acc[t] = __builtin_amdgcn_mfma_f32_32x32x16_bf16(afrag, bfrag, acc[t], 0, 0, 0);
        }
    }

    int g0 = row0 / SEG;
    int bnd = (g0 + 1) * SEG;
    int straddle = (row0 + 31 >= bnd);

#pragma unroll
    for (int t = 0; t < 2; ++t) {
        float s0 = 0.f, s1 = 0.f;
#pragma unroll
        for (int r = 0; r < 16; ++r) {
            int row = row0 + (r & 3) + 8 * (r >> 2) + 4 * half;
            float v = fmaxf(acc[t][r] + bb[t], 0.f);
            if (row < bnd) s0 += v; else s1 += v;
        }
        s0 += __shfl_xor(s0, 32);
        s1 += __shfl_xor(s1, 32);
        if (half == 0) {
            int coln = nh * 64 + t * 32 + m;
            atomicAdd(&pooled[g0 * HDIM + coln], s0);
            if (straddle) atomicAdd(&pooled[(g0 + 1) * HDIM + coln], s1);
        }
    }
}

// ---------------- mixup: bf16 y -> Abuf right half ----------------

__global__ void k_mixup_toA(const ushort_t* __restrict__ y, const int* __restrict__ perm,
                            const float* __restrict__ lam, ushort_t* __restrict__ Abuf) {
    int idx = blockIdx.x * 256 + threadIdx.x;
    int row = idx >> 5;
    int c4 = (idx & 31) * 4;
    float l = lam[0];
    float om = 1.f - l;
    int p = perm[row];
    ushort4 a = *(const ushort4*)(y + (size_t)row * HDIM + c4);
    ushort4 b = *(const ushort4*)(y + (size_t)p * HDIM + c4);
    ushort4 o;
    o.x = f2bf(l * bf2f(a.x) + om * bf2f(b.x));
    o.y = f2bf(l * bf2f(a.y) + om * bf2f(b.y));
    o.z = f2bf(l * bf2f(a.z) + om * bf2f(b.z));
    o.w = f2bf(l * bf2f(a.w) + om * bf2f(b.w));
    *(ushort4*)(Abuf + (size_t)row * AK + HDIM + c4) = o;
}

// ---------------- final: linear + log_softmax from pooled ----------------

__global__ __launch_bounds__(64) void k_final(const float* __restrict__ pooled,
                                              const float* __restrict__ Wlin,
                                              const float* __restrict__ blin,
                                              float* __restrict__ out) {
    int g = blockIdx.x;
    int lane = threadIdx.x;
    float2 v = *(const float2*)(pooled + (size_t)g * HDIM + lane * 2);
    float p[NOUT];
#pragma unroll
    for (int o = 0; o < NOUT; ++o)
        p[o] = v.x * Wlin[(size_t)(2 * lane) * NOUT + o] +
               v.y * Wlin[(size_t)(2 * lane + 1) * NOUT + o];
#pragma unroll
    for (int mask = 1; mask < 64; mask <<= 1)
#pragma unroll
        for (int o = 0; o < NOUT; ++o) p[o] += __shfl_xor(p[o], mask);
    if (lane == 0) {
        float lg[NOUT];
        float mx = -1e30f;
#pragma unroll
        for (int o = 0; o < NOUT; ++o) { lg[o] = p[o] + blin[o]; mx = fmaxf(mx, lg[o]); }
        float se = 0.f;
#pragma unroll
        for (int o = 0; o < NOUT; ++o) se += expf(lg[o] - mx);
        float lse = mx + logf(se);
#pragma unroll
        for (int o = 0; o < NOUT; ++o) out[g * NOUT + o] = lg[o] - lse;
    }
}

// ---------------- host ----------------

extern "C" void kernel_launch(void* const* d_in, const int* in_sizes, int n_in,
                              void* d_out, int out_size, void* d_ws, size_t ws_size,
                              hipStream_t stream) {
    const float* x0     = (const float*)d_in[0];
    const int*   edge   = (const int*)d_in[1];
    const int*   src    = edge;
    const int*   dst    = edge + N_EDGES;
    const float* lam    = (const float*)d_in[2];
    const int*   perm1  = (const int*)d_in[5];
    const int*   perm2  = (const int*)d_in[6];
    const float* W1_rel = (const float*)d_in[8];
    const float* b1_rel = (const float*)d_in[9];
    const float* W1_root= (const float*)d_in[10];
    const float* W2_rel = (const float*)d_in[11];
    const float* b2_rel = (const float*)d_in[12];
    const float* W2_root= (const float*)d_in[13];
    const float* W_lin  = (const float*)d_in[14];
    const float* b_lin  = (const float*)d_in[15];
    float* out = (float*)d_out;

    char* w = (char*)d_ws;
    size_t off = 0;
    auto alloc = [&](size_t bytes) -> void* {
        void* p = w + off;
        off = (off + bytes + 255) & ~(size_t)255;
        return p;
    };
    int* cnt       = (int*)alloc((size_t)N_NODES * 4);
    ushort_t* col2 = (ushort_t*)alloc((size_t)N_NODES * SLOT * 2);
    ushort_t* Abuf   = (ushort_t*)alloc((size_t)N_NODES * AK * 2);
    ushort_t* ybuf   = (ushort_t*)alloc((size_t)N_NODES * HDIM * 2);
    ushort_t* Wfrag1 = (ushort_t*)alloc(32768 * 2);
    ushort_t* Wfrag2 = (ushort_t*)alloc(32768 * 2);
    float* pooled    = (float*)alloc((size_t)NGRAPH * HDIM * 4);

    // prep first (zeroes cnt + pooled, casts x0, builds Wfrags) — no memset dispatch
    k_prep<<<6920, 256, 0, stream>>>(x0, Abuf, W1_rel, W1_root, W2_rel, W2_root,
                                     Wfrag1, Wfrag2, pooled, cnt);
    // CSR build: one scatter kernel, 4 edges/thread
    k_scatter<<<N_EDGES / 1024, 256, 0, stream>>>(src, dst, cnt, col2);

    const int aggGrid  = N_NODES / 4;
    const int gemmGrid = (N_NODES / 32) * 2;
    const int elGrid   = (N_NODES * HDIM / 4) / 256;

    // layer 1
    k_aggregate<<<aggGrid, 256, 0, stream>>>(Abuf, cnt, col2);
    k_gemm_mfma<<<gemmGrid, 64, 0, stream>>>(Abuf, Wfrag1, b1_rel, ybuf);
    k_mixup_toA<<<elGrid, 256, 0, stream>>>(ybuf, perm1, lam, Abuf);
    // layer 2
    k_aggregate<<<aggGrid, 256, 0, stream>>>(Abuf, cnt, col2);
    k_gemm_mfma<<<gemmGrid, 64, 0, stream>>>(Abuf, Wfrag2, b2_rel, ybuf);
    k_mixup_toA<<<elGrid, 256, 0, stream>>>(ybuf, perm2, lam, Abuf);
    // layer 3 (mixup3 is a pooling no-op -> fused pool)
    k_aggregate<<<aggGrid, 256, 0, stream>>>(Abuf, cnt, col2);
    k_gemm_pool<<<gemmGrid, 64, 0, stream>>>(Abuf, Wfrag2, b2_rel, pooled);

    // classifier + log_softmax
    k_final<<<NGRAPH, 64, 0, stream>>>(pooled, W_lin, b_lin, out);
}